// Round 4
// baseline (411.647 us; speedup 1.0000x reference)
//
#include <hip/hip_runtime.h>

#define BATCH      4096
#define FILTER_NUM 1024
#define REL_CNT    19
#define REL_DIM    1024
#define SLAB       (FILTER_NUM * REL_CNT)   // 19456 floats per batch
#define ITERS      (SLAB / (256 * 4))       // 19 exactly
#define SPB        4                        // slabs (batches) per block

typedef float vf4 __attribute__((ext_vector_type(4)));

// Kernel 1: V[f,r] = sum_e U[f,e] * R[r,e]   (V = U @ R^T, [1024 x 19])
__global__ __launch_bounds__(256) void compute_V_kernel(
        const float* __restrict__ U,   // [FILTER_NUM, REL_DIM]
        const float* __restrict__ Rm,  // [REL_CNT, REL_DIM]
        float* __restrict__ V)         // [FILTER_NUM, REL_CNT]
{
    const int f   = blockIdx.x;
    const int tid = threadIdx.x;

    float acc[REL_CNT];
#pragma unroll
    for (int r = 0; r < REL_CNT; ++r) acc[r] = 0.0f;

    const float* __restrict__ Urow = U + (size_t)f * REL_DIM;
    for (int e = tid; e < REL_DIM; e += 256) {
        const float u = Urow[e];
#pragma unroll
        for (int r = 0; r < REL_CNT; ++r)
            acc[r] = fmaf(u, Rm[r * REL_DIM + e], acc[r]);
    }

    __shared__ float s[4][REL_CNT];
    const int lane = tid & 63;
    const int wave = tid >> 6;
#pragma unroll
    for (int r = 0; r < REL_CNT; ++r) {
        float v = acc[r];
#pragma unroll
        for (int off = 32; off > 0; off >>= 1)
            v += __shfl_down(v, off, 64);
        if (lane == 0) s[wave][r] = v;
    }
    __syncthreads();
    if (tid < REL_CNT)
        V[f * REL_CNT + tid] = s[0][tid] + s[1][tid] + s[2][tid] + s[3][tid];
}

// Kernel 2: SPB batch slabs per block; each v4 load serves SPB conv streams.
// conv loads are nontemporal (read-once stream). Static phase rotation:
// element k of float4 idx has r = (17*iter + o + k) % 19, o = (4*tid) % 19.
__global__ __launch_bounds__(256) void score_kernel(
        const float* __restrict__ conv,  // [BATCH, FILTER_NUM, REL_CNT]
        const float* __restrict__ V,     // [FILTER_NUM, REL_CNT] flat
        float* __restrict__ out)         // [BATCH, REL_CNT]
{
    const int b0  = blockIdx.x * SPB;
    const int tid = threadIdx.x;

    const vf4* __restrict__ c4 = (const vf4*)(conv + (size_t)b0 * SLAB);
    const vf4* __restrict__ v4 = (const vf4*)V;

    const int o = (4 * tid) % REL_CNT;

    float acc[SPB][REL_CNT];
#pragma unroll
    for (int m = 0; m < SPB; ++m)
#pragma unroll
        for (int j = 0; j < REL_CNT; ++j) acc[m][j] = 0.0f;

#pragma unroll
    for (int iter = 0; iter < ITERS; ++iter) {
        const int idx = iter * 256 + tid;
        const vf4 v = v4[idx];
        vf4 x[SPB];
#pragma unroll
        for (int m = 0; m < SPB; ++m)
            x[m] = __builtin_nontemporal_load(&c4[idx + m * (SLAB / 4)]);
        const int j0 = (17 * iter + 0) % REL_CNT;
        const int j1 = (17 * iter + 1) % REL_CNT;
        const int j2 = (17 * iter + 2) % REL_CNT;
        const int j3 = (17 * iter + 3) % REL_CNT;
#pragma unroll
        for (int m = 0; m < SPB; ++m) {
            acc[m][j0] = fmaf(x[m].x, v.x, acc[m][j0]);
            acc[m][j1] = fmaf(x[m].y, v.y, acc[m][j1]);
            acc[m][j2] = fmaf(x[m].z, v.z, acc[m][j2]);
            acc[m][j3] = fmaf(x[m].w, v.w, acc[m][j3]);
        }
    }

    // LDS reduction per slab (s/s2 reused; barriers order the phases).
    __shared__ float s[256 * REL_CNT];
    __shared__ float s2[8 * REL_CNT];

#pragma unroll
    for (int m = 0; m < SPB; ++m) {
        if (m > 0) __syncthreads();   // protect s/s2 from previous slab's readers
#pragma unroll
        for (int j = 0; j < REL_CNT; ++j) {
            int r = o + j; if (r >= REL_CNT) r -= REL_CNT;
            s[tid * REL_CNT + r] = acc[m][j];
        }
        __syncthreads();
        if (tid < 8 * REL_CNT) {
            const int r = tid % REL_CNT;
            const int g = tid / REL_CNT;
            float sum = 0.0f;
#pragma unroll
            for (int i = 0; i < 32; ++i)
                sum += s[(g * 32 + i) * REL_CNT + r];
            s2[g * REL_CNT + r] = sum;
        }
        __syncthreads();
        if (tid < REL_CNT) {
            float sum = 0.0f;
#pragma unroll
            for (int g = 0; g < 8; ++g) sum += s2[g * REL_CNT + tid];
            out[(b0 + m) * REL_CNT + tid] = sum;
        }
    }
}

extern "C" void kernel_launch(void* const* d_in, const int* in_sizes, int n_in,
                              void* d_out, int out_size, void* d_ws, size_t ws_size,
                              hipStream_t stream) {
    // setup_inputs order: conv_output [B,F,R], R_output [R,E], U [F,E] — all fp32
    const float* conv = (const float*)d_in[0];
    const float* Rm   = (const float*)d_in[1];
    const float* U    = (const float*)d_in[2];
    float*       out  = (float*)d_out;
    float*       V    = (float*)d_ws;   // FILTER_NUM*REL_CNT floats

    compute_V_kernel<<<FILTER_NUM, 256, 0, stream>>>(U, Rm, V);
    score_kernel<<<BATCH / SPB, 256, 0, stream>>>(conv, V, out);
}